// Round 1
// baseline (64.946 us; speedup 1.0000x reference)
//
#include <hip/hip_runtime.h>
#include <hip/hip_bf16.h>

// Problem: b=8, H=8 heads, n=1024 tokens, d=32 head-dim, fp32 in, scalar loss out.
// Memory layout per (b,h) pair p: Qt[d][n] = f_s[p*32768 + d*1024 + n] (contiguous in n).
// sim = Q K^T (no scaling), softmax over j, out = P V, loss = mean((out - f_t)^2).

typedef __attribute__((ext_vector_type(4))) float f32x4;
typedef __attribute__((ext_vector_type(8))) short bf16x8;

#define LDS_K 8192
#define LDS_V 12288
#define LDS_P 16384
#define LDS_R 32768

__device__ __forceinline__ unsigned bfpack2(float a, float b) {
    // RNE f32->bf16 pair pack (inputs are finite; no NaN handling needed)
    unsigned ua = __float_as_uint(a), ub = __float_as_uint(b);
    ua += 0x7fffu + ((ua >> 16) & 1u);
    ub += 0x7fffu + ((ub >> 16) & 1u);
    return (ua >> 16) | (ub & 0xffff0000u);
}

__global__ __launch_bounds__(256, 2)
void attn_mse_kernel(const float* __restrict__ fs, const float* __restrict__ ft,
                     float* __restrict__ out)
{
    __shared__ __align__(16) unsigned char smem[32768 + 16];

    const int tid  = threadIdx.x;
    const int lane = tid & 63;
    const int w    = tid >> 6;      // wave 0..3
    const int g    = lane >> 4;     // 0..3
    const int c    = lane & 15;

    const int pair = blockIdx.x >> 3;        // (b,h) pair 0..63
    const int q0   = (blockIdx.x & 7) * 128; // this block's first query row

    const float* qb = fs + (size_t)pair * 32768;  // Q and V source (f_s tokens)
    const float* kb = ft + (size_t)pair * 32768;  // K source (f_t tokens)

    unsigned* lq = (unsigned*)smem;

    // ---- stage Q in MFMA chunk layout; wave w owns subtiles 2w, 2w+1 (16 rows each).
    // chunk(gd, i) = Q[row0+i][8gd..8gd+7] as 16B; write addr/4 = i*4 + g: conflict-free.
    #pragma unroll
    for (int s = 0; s < 2; ++s) {
        const int sub  = 2 * w + s;
        const int row0 = q0 + sub * 16;
        #pragma unroll
        for (int p = 0; p < 4; ++p) {
            const int dp = 4 * p + g;  // d-pair index 0..15
            const float* src = qb + (size_t)(2 * dp) * 1024 + row0 + c;
            lq[sub * 256 + p * 64 + c * 4 + g] = bfpack2(src[0], src[1024]);
        }
    }
    // wave reads only its own staged region -> no barrier needed (lgkmcnt ordering)
    const bf16x8 qf0 = *(const bf16x8*)(smem + (2 * w + 0) * 1024 + lane * 16);
    const bf16x8 qf1 = *(const bf16x8*)(smem + (2 * w + 1) * 1024 + lane * 16);

    f32x4 O[2][2]; // [i-subtile][d-subtile], rows i = 4g+reg, col d = c (C/D layout)
    #pragma unroll
    for (int a = 0; a < 2; ++a)
        #pragma unroll
        for (int b = 0; b < 2; ++b)
            O[a][b] = f32x4{0.f, 0.f, 0.f, 0.f};
    float l_run0 = 0.f, l_run1 = 0.f;  // unnormalized softmax denominators (i = Nt*16 + c)

    unsigned* lk = (unsigned*)(smem + LDS_K);
    unsigned char* lv = smem + LDS_V;
    unsigned char* lp = smem + LDS_P + w * 4096;  // per-wave P tile [32 i][64 j] bf16

    for (int t = 0; t < 16; ++t) {
        const int j0 = t * 64;

        // ---- stage K subtile w (KV rows j0+16w..+15), same chunk layout as Q
        {
            const int row0 = j0 + w * 16;
            #pragma unroll
            for (int p = 0; p < 4; ++p) {
                const int dp = 4 * p + g;
                const float* src = kb + (size_t)(2 * dp) * 1024 + row0 + c;
                lk[w * 256 + p * 64 + c * 4 + g] = bfpack2(src[0], src[1024]);
            }
        }
        // ---- stage V rows d=8w..8w+7, natural [d][64] bf16, XOR-swizzled rows
        {
            #pragma unroll
            for (int p = 0; p < 4; ++p) {
                const int d  = 8 * w + 4 * (p & 1) + g;
                const int np = p >> 1;
                const int nl = c * 2 + np * 32;
                const float2 v2 = *(const float2*)(qb + (size_t)d * 1024 + j0 + nl);
                const unsigned byte = d * 128 + ((nl * 2) ^ ((d & 7) << 4));
                *(unsigned*)(lv + byte) = bfpack2(v2.x, v2.y);
            }
        }
        __syncthreads();

        // ---- ST = K * Q^T: D[j_local][i_local]; lane holds rows 4g+r (j), col c (i)
        f32x4 S[4][2];
        #pragma unroll
        for (int Mt = 0; Mt < 4; ++Mt) {
            const bf16x8 kf = *(const bf16x8*)(smem + LDS_K + Mt * 1024 + lane * 16);
            const f32x4 z = {0.f, 0.f, 0.f, 0.f};
            S[Mt][0] = __builtin_amdgcn_mfma_f32_16x16x32_bf16(kf, qf0, z, 0, 0, 0);
            S[Mt][1] = __builtin_amdgcn_mfma_f32_16x16x32_bf16(kf, qf1, z, 0, 0, 0);
        }

        // ---- P = exp(S) (no max subtraction: |S| <= ~34, safely in fp32/bf16 range)
        {
            float ps0 = 0.f, ps1 = 0.f;
            #pragma unroll
            for (int Mt = 0; Mt < 4; ++Mt)
                #pragma unroll
                for (int r = 0; r < 4; ++r) {
                    float p0 = __expf(S[Mt][0][r]);
                    float p1 = __expf(S[Mt][1][r]);
                    S[Mt][0][r] = p0; ps0 += p0;
                    S[Mt][1][r] = p1; ps1 += p1;
                }
            l_run0 += ps0;  // in-lane partial over j = Mt*16 + 4g + r; g-reduce deferred
            l_run1 += ps1;
        }

        // ---- write P^T values into per-wave P tile [i][j] (4 consecutive j per b64)
        #pragma unroll
        for (int Nt = 0; Nt < 2; ++Nt) {
            const int row = Nt * 16 + c;
            #pragma unroll
            for (int Mt = 0; Mt < 4; ++Mt) {
                const unsigned lo = bfpack2(S[Mt][Nt][0], S[Mt][Nt][1]);
                const unsigned hi = bfpack2(S[Mt][Nt][2], S[Mt][Nt][3]);
                const unsigned byte = row * 128 + (((unsigned)(Mt * 32 + g * 8)) ^ ((c & 7) << 4));
                *(unsigned long long*)(lp + byte) =
                    (unsigned long long)lo | ((unsigned long long)hi << 32);
            }
        }

        // ---- O += P * V  (A = P [16i][32j] from lp, B = V [32j][16d] from lv)
        #pragma unroll
        for (int ks = 0; ks < 2; ++ks) {
            const unsigned cb = ((unsigned)(ks * 64 + g * 16)) ^ ((c & 7) << 4);
            const bf16x8 pa0 = *(const bf16x8*)(lp + (0 * 16 + c) * 128 + cb);
            const bf16x8 pa1 = *(const bf16x8*)(lp + (1 * 16 + c) * 128 + cb);
            const bf16x8 vb0 = *(const bf16x8*)(lv + (0 * 16 + c) * 128 + cb);
            const bf16x8 vb1 = *(const bf16x8*)(lv + (1 * 16 + c) * 128 + cb);
            O[0][0] = __builtin_amdgcn_mfma_f32_16x16x32_bf16(pa0, vb0, O[0][0], 0, 0, 0);
            O[0][1] = __builtin_amdgcn_mfma_f32_16x16x32_bf16(pa0, vb1, O[0][1], 0, 0, 0);
            O[1][0] = __builtin_amdgcn_mfma_f32_16x16x32_bf16(pa1, vb0, O[1][0], 0, 0, 0);
            O[1][1] = __builtin_amdgcn_mfma_f32_16x16x32_bf16(pa1, vb1, O[1][1], 0, 0, 0);
        }
        __syncthreads();
    }

    // ---- finish softmax denominators (reduce over g-groups) and compute loss
    l_run0 += __shfl_xor(l_run0, 16); l_run0 += __shfl_xor(l_run0, 32);
    l_run1 += __shfl_xor(l_run1, 16); l_run1 += __shfl_xor(l_run1, 32);
    const float li0 = 1.0f / l_run0;
    const float li1 = 1.0f / l_run1;

    float acc = 0.f;
    const int n0 = q0 + w * 32;
    #pragma unroll
    for (int Mi = 0; Mi < 2; ++Mi) {
        const float liv = Mi ? li1 : li0;
        #pragma unroll
        for (int r = 0; r < 4; ++r) {
            const float lr = __shfl(liv, g * 4 + r);  // denom for row i_local = 4g+r
            const int n = n0 + Mi * 16 + g * 4 + r;
            #pragma unroll
            for (int Nd = 0; Nd < 2; ++Nd) {
                const int d = Nd * 16 + c;
                const float oo = O[Mi][Nd][r] * lr;
                const float tv = kb[(size_t)d * 1024 + n];
                const float e = oo - tv;
                acc += e * e;
            }
        }
    }
    #pragma unroll
    for (int off = 1; off < 64; off <<= 1) acc += __shfl_xor(acc, off);
    float* lred = (float*)(smem + LDS_R);
    if (lane == 0) lred[w] = acc;
    __syncthreads();
    if (tid == 0)
        atomicAdd(out, (lred[0] + lred[1] + lred[2] + lred[3]) * (1.0f / 2097152.0f));
}

extern "C" void kernel_launch(void* const* d_in, const int* in_sizes, int n_in,
                              void* d_out, int out_size, void* d_ws, size_t ws_size,
                              hipStream_t stream) {
    const float* fs = (const float*)d_in[0];
    const float* ft = (const float*)d_in[1];
    float* out = (float*)d_out;
    hipMemsetAsync(out, 0, sizeof(float), stream);
    attn_mse_kernel<<<dim3(512), dim3(256), 0, stream>>>(fs, ft, out);
}

// Round 2
// 37.527 us; speedup vs baseline: 1.7306x; 1.7306x over previous
//
#include <hip/hip_runtime.h>
#include <hip/hip_bf16.h>

// b=8, H=8, n=1024, d=32, fp32 in, scalar MSE loss out.
// Per (b,h) pair p: Qt[d][n] = f_s[p*32768 + d*1024 + n]. sim = QK^T (unscaled),
// softmax over j, out = PV, loss = mean((out - f_t)^2).
//
// Block = 512 thr (8 waves), 128 q-rows/block (16 rows/wave). Grid = 512 with
// XCD swizzle (8 q-blocks of a pair share bid%8 -> 2MB/XCD L2 working set).
// Double-buffered K/V tiles (64 KV rows), register prefetch, 1 barrier/tile.

typedef __attribute__((ext_vector_type(4))) float f32x4;
typedef __attribute__((ext_vector_type(8))) short bf16x8;

#define QOFF 0         // 8 subtiles x 1KB (chunk layout, per-wave)
#define KOFF 8192      // 2 x 4KB double buffer (chunk layout)
#define VOFF 16384     // 2 x 4KB double buffer ([d][j] bf16, XOR-swizzled rows)
#define POFF 24576     // 8 waves x 2KB ([16 i][64 j] bf16, XOR-swizzled rows)
#define ROFF 40960     // 8 floats block reduction

__device__ __forceinline__ unsigned bfpack2(float a, float b) {
    // RNE f32->bf16 pair pack (finite inputs)
    unsigned ua = __float_as_uint(a), ub = __float_as_uint(b);
    ua += 0x7fffu + ((ua >> 16) & 1u);
    ub += 0x7fffu + ((ub >> 16) & 1u);
    return (ua >> 16) | (ub & 0xffff0000u);
}

__global__ __launch_bounds__(512, 4)
void attn_mse_kernel(const float* __restrict__ fs, const float* __restrict__ ft,
                     float* __restrict__ out)
{
    __shared__ __align__(16) unsigned char smem[41024];

    const int tid  = threadIdx.x;
    const int lane = tid & 63;
    const int w    = tid >> 6;     // wave 0..7
    const int g    = lane >> 4;    // 0..3
    const int c    = lane & 15;

    // XCD-aware swizzle: dispatch maps bid -> XCD bid%8. Give each XCD 8 whole
    // pairs (all their q-blocks) so K/V stay L2-resident.
    const int bid  = blockIdx.x;
    const int x    = bid & 7, y = bid >> 3;
    const int pair = x * 8 + (y & 7);       // 0..63
    const int q0   = (y >> 3) * 128;        // q-block base row

    const float* qb = fs + (size_t)pair * 32768;  // Q and V source
    const float* kb = ft + (size_t)pair * 32768;  // K source (and loss target)

    // ---- stage Q rows q0 + w*16 .. +15 (own-wave region; no barrier needed)
    {
        unsigned* lq = (unsigned*)(smem + QOFF) + w * 256;
        const int row0 = q0 + w * 16;
        #pragma unroll
        for (int p = 0; p < 4; ++p) {
            const int dp = 4 * p + g;  // d-pair 0..15
            const float* src = qb + (size_t)(2 * dp) * 1024 + row0 + c;
            lq[p * 64 + c * 4 + g] = bfpack2(src[0], src[1024]);
        }
    }
    const bf16x8 qf = *(const bf16x8*)(smem + QOFF + w * 1024 + lane * 16);

    const int  kq  = w & 3;
    const bool isK = (w < 4);   // waves 0..3 stage K subtiles, 4..7 stage V rows

    float rr[8];  // prefetch registers

    // LOAD: global -> regs for tile t; STORE: regs -> LDS buf
    auto LOAD = [&](int t) {
        if (isK) {
            const int row0 = t * 64 + kq * 16;
            #pragma unroll
            for (int p = 0; p < 4; ++p) {
                const int dp = 4 * p + g;
                const float* src = kb + (size_t)(2 * dp) * 1024 + row0 + c;
                rr[2 * p] = src[0]; rr[2 * p + 1] = src[1024];
            }
        } else {
            #pragma unroll
            for (int p = 0; p < 4; ++p) {
                const int d  = 8 * kq + 4 * (p & 1) + g;
                const int nl = c * 2 + (p >> 1) * 32;
                const float2 v2 = *(const float2*)(qb + (size_t)d * 1024 + t * 64 + nl);
                rr[2 * p] = v2.x; rr[2 * p + 1] = v2.y;
            }
        }
    };
    auto STORE = [&](int buf) {
        if (isK) {
            unsigned* lk = (unsigned*)(smem + KOFF + buf * 4096) + kq * 256;
            #pragma unroll
            for (int p = 0; p < 4; ++p)
                lk[p * 64 + c * 4 + g] = bfpack2(rr[2 * p], rr[2 * p + 1]);
        } else {
            unsigned char* lv = smem + VOFF + buf * 4096;
            #pragma unroll
            for (int p = 0; p < 4; ++p) {
                const int d  = 8 * kq + 4 * (p & 1) + g;
                const int nl = c * 2 + (p >> 1) * 32;
                *(unsigned*)(lv + d * 128 + ((nl * 2) ^ ((d & 7) << 4))) =
                    bfpack2(rr[2 * p], rr[2 * p + 1]);
            }
        }
    };

    LOAD(0);
    STORE(0);

    f32x4 O0 = {0.f, 0.f, 0.f, 0.f}, O1 = {0.f, 0.f, 0.f, 0.f};
    float l_run = 0.f;                       // denom partial for q-row i = c
    unsigned char* lp = smem + POFF + w * 2048;

    int cur = 0;
    for (int t = 0; t < 16; ++t) {
        if (t < 15) LOAD(t + 1);             // issue early: latency hides under compute
        __syncthreads();                     // buf[cur] ready (writes from prev iter)
        const unsigned char* bK = smem + KOFF + cur * 4096;
        const unsigned char* bV = smem + VOFF + cur * 4096;

        // ST = K * Q^T : lane holds j = Mt*16 + 4g + r, i = c
        f32x4 S[4];
        #pragma unroll
        for (int Mt = 0; Mt < 4; ++Mt) {
            const bf16x8 kf = *(const bf16x8*)(bK + Mt * 1024 + lane * 16);
            const f32x4 z = {0.f, 0.f, 0.f, 0.f};
            S[Mt] = __builtin_amdgcn_mfma_f32_16x16x32_bf16(kf, qf, z, 0, 0, 0);
        }

        // P = exp(S) (no max subtraction: |S| <= ~34, fp32-safe)
        float ps = 0.f;
        #pragma unroll
        for (int Mt = 0; Mt < 4; ++Mt)
            #pragma unroll
            for (int rI = 0; rI < 4; ++rI) {
                const float p = __expf(S[Mt][rI]);
                S[Mt][rI] = p; ps += p;
            }
        l_run += ps;

        // P^T into per-wave tile [i=c][j] (wave-local; in-order LDS, no barrier)
        #pragma unroll
        for (int Mt = 0; Mt < 4; ++Mt) {
            const unsigned lo = bfpack2(S[Mt][0], S[Mt][1]);
            const unsigned hi = bfpack2(S[Mt][2], S[Mt][3]);
            *(unsigned long long*)(lp + c * 128 +
                (((unsigned)(Mt * 32 + g * 8)) ^ ((c & 7) << 4))) =
                (unsigned long long)lo | ((unsigned long long)hi << 32);
        }

        // O += P * V
        #pragma unroll
        for (int ks = 0; ks < 2; ++ks) {
            const unsigned cb = ((unsigned)(ks * 64 + g * 16)) ^ ((c & 7) << 4);
            const bf16x8 pa  = *(const bf16x8*)(lp + c * 128 + cb);
            const bf16x8 vb0 = *(const bf16x8*)(bV + c * 128 + cb);
            const bf16x8 vb1 = *(const bf16x8*)(bV + (c + 16) * 128 + cb);
            O0 = __builtin_amdgcn_mfma_f32_16x16x32_bf16(pa, vb0, O0, 0, 0, 0);
            O1 = __builtin_amdgcn_mfma_f32_16x16x32_bf16(pa, vb1, O1, 0, 0, 0);
        }

        if (t < 15) STORE(cur ^ 1);          // fill next buffer (read next iter, post-barrier)
        cur ^= 1;
    }

    // ---- softmax denominators (reduce over g groups; all lanes get row c's sum)
    l_run += __shfl_xor(l_run, 16);
    l_run += __shfl_xor(l_run, 32);
    const float li = 1.0f / l_run;

    // ---- loss: lane holds O rows i = 4g+r, cols d = c / c+16
    float acc = 0.f;
    const int n0 = q0 + w * 16;
    #pragma unroll
    for (int rI = 0; rI < 4; ++rI) {
        const float lr = __shfl(li, g * 4 + rI);  // denom of row 4g+rI (lane c=4g+rI,g=0)
        const int n = n0 + g * 4 + rI;
        #pragma unroll
        for (int Nd = 0; Nd < 2; ++Nd) {
            const int d = Nd * 16 + c;
            const float oo = (Nd ? O1[rI] : O0[rI]) * lr;
            const float tv = kb[(size_t)d * 1024 + n];
            const float e = oo - tv;
            acc += e * e;
        }
    }
    #pragma unroll
    for (int off = 1; off < 64; off <<= 1) acc += __shfl_xor(acc, off);
    float* lred = (float*)(smem + ROFF);
    if (lane == 0) lred[w] = acc;
    __syncthreads();
    if (tid == 0) {
        float s = 0.f;
        #pragma unroll
        for (int i = 0; i < 8; ++i) s += lred[i];
        atomicAdd(out, s * (1.0f / 2097152.0f));
    }
}

extern "C" void kernel_launch(void* const* d_in, const int* in_sizes, int n_in,
                              void* d_out, int out_size, void* d_ws, size_t ws_size,
                              hipStream_t stream) {
    const float* fs = (const float*)d_in[0];
    const float* ft = (const float*)d_in[1];
    float* out = (float*)d_out;
    hipMemsetAsync(out, 0, sizeof(float), stream);
    attn_mse_kernel<<<dim3(512), dim3(512), 0, stream>>>(fs, ft, out);
}